// Round 1
// baseline (981.823 us; speedup 1.0000x reference)
//
#include <hip/hip_runtime.h>
#include <math.h>

// Problem constants
#define PB 4
#define PS 8192
#define PD 1024
#define PNF 256
#define PF2 (2 * PNF)          // 512
#define PM (PB * PS)           // 32768 rows

// Scan chunking: |A| < 0.5 => A^32 < 2.4e-10, warm-up of 32 steps is exact to fp32
#define CHUNK_L 128
#define WARM_W 32
#define NCHUNK (PS / CHUNK_L)  // 64

#define BM 128
#define BN 128
#define BK 16

// C[M,N] = A[M,K] * Bt[N,K]^T   (both operands K-contiguous, "NT" GEMM)
__global__ __launch_bounds__(256) void gemm_nt_f32(
    const float* __restrict__ A, const float* __restrict__ Bt,
    float* __restrict__ C, int M, int N, int K) {
  __shared__ float As[BK][BM + 4];
  __shared__ float Bs[BK][BN + 4];
  const int t = threadIdx.x;
  const int bm = blockIdx.y * BM;
  const int bn = blockIdx.x * BN;
  const int r0 = (t >> 4) * 8;   // 16x16 thread grid, 8x8 outputs each
  const int c0 = (t & 15) * 8;
  const int lr = t >> 1;         // loader row 0..127
  const int lc = (t & 1) * 8;    // loader col 0 or 8
  const float* Ap = A + (size_t)(bm + lr) * K + lc;
  const float* Bp = Bt + (size_t)(bn + lr) * K + lc;

  float4 av0 = *(const float4*)(Ap);
  float4 av1 = *(const float4*)(Ap + 4);
  float4 bv0 = *(const float4*)(Bp);
  float4 bv1 = *(const float4*)(Bp + 4);

  float acc[8][8];
#pragma unroll
  for (int i = 0; i < 8; ++i)
#pragma unroll
    for (int j = 0; j < 8; ++j) acc[i][j] = 0.f;

  for (int k0 = 0; k0 < K; k0 += BK) {
    __syncthreads();
    As[lc + 0][lr] = av0.x; As[lc + 1][lr] = av0.y;
    As[lc + 2][lr] = av0.z; As[lc + 3][lr] = av0.w;
    As[lc + 4][lr] = av1.x; As[lc + 5][lr] = av1.y;
    As[lc + 6][lr] = av1.z; As[lc + 7][lr] = av1.w;
    Bs[lc + 0][lr] = bv0.x; Bs[lc + 1][lr] = bv0.y;
    Bs[lc + 2][lr] = bv0.z; Bs[lc + 3][lr] = bv0.w;
    Bs[lc + 4][lr] = bv1.x; Bs[lc + 5][lr] = bv1.y;
    Bs[lc + 6][lr] = bv1.z; Bs[lc + 7][lr] = bv1.w;
    __syncthreads();
    if (k0 + BK < K) {  // prefetch next K-tile; latency hides under compute
      av0 = *(const float4*)(Ap + k0 + BK);
      av1 = *(const float4*)(Ap + k0 + BK + 4);
      bv0 = *(const float4*)(Bp + k0 + BK);
      bv1 = *(const float4*)(Bp + k0 + BK + 4);
    }
#pragma unroll
    for (int kk = 0; kk < BK; ++kk) {
      float4 a0 = *(const float4*)&As[kk][r0];
      float4 a1 = *(const float4*)&As[kk][r0 + 4];
      float4 b0 = *(const float4*)&Bs[kk][c0];
      float4 b1 = *(const float4*)&Bs[kk][c0 + 4];
      float a[8] = {a0.x, a0.y, a0.z, a0.w, a1.x, a1.y, a1.z, a1.w};
      float b[8] = {b0.x, b0.y, b0.z, b0.w, b1.x, b1.y, b1.z, b1.w};
#pragma unroll
      for (int i = 0; i < 8; ++i)
#pragma unroll
        for (int j = 0; j < 8; ++j)
          acc[i][j] = fmaf(a[i], b[j], acc[i][j]);
    }
  }
#pragma unroll
  for (int i = 0; i < 8; ++i) {
    float* Cp = C + (size_t)(bm + r0 + i) * N + (bn + c0);
    float4 o0 = {acc[i][0], acc[i][1], acc[i][2], acc[i][3]};
    float4 o1 = {acc[i][4], acc[i][5], acc[i][6], acc[i][7]};
    *(float4*)Cp = o0;
    *(float4*)(Cp + 4) = o1;
  }
}

// Pass 1: compute chunk-entry states via 32-step warm-up (read-only => no race
// with the in-place overwrite of pass 2).
__global__ __launch_bounds__(256) void scan_warm(
    const float* __restrict__ sp, const float* __restrict__ log_decay,
    const float* __restrict__ freq, float2* __restrict__ H) {
  const int f = threadIdx.x;   // 0..255 feature
  const int c = blockIdx.x;    // chunk
  const int b = blockIdx.y;    // batch
  const float decay = 1.0f / (1.0f + expf(-log_decay[f]));
  const float om = freq[f] * 0.1f;
  const float Ar = decay * cosf(om);
  const float Ai = decay * sinf(om);
  const int t0 = c * CHUNK_L;
  const int tw = (t0 - WARM_W > 0) ? (t0 - WARM_W) : 0;
  const float* base = sp + (size_t)b * PS * PF2;
  float hr = 0.f, hi = 0.f;
  for (int t = tw; t < t0; ++t) {
    const float* p = base + (size_t)t * PF2;
    float ur = p[f];
    float ui = p[PNF + f];
    float pr = fmaf(Ar, hr, fmaf(-Ai, hi, ur));
    float pi = fmaf(Ar, hi, fmaf(Ai, hr, ui));
    hr = pr; hi = pi;
  }
  H[((size_t)b * NCHUNK + c) * PNF + f] = make_float2(hr, hi);
}

// Pass 2: run the recurrence over the chunk from the warm state, multiply by
// rot, write feats IN PLACE over spectral (each thread owns cols f and f+NF).
__global__ __launch_bounds__(256) void scan_main(
    float* __restrict__ sp, const float* __restrict__ log_decay,
    const float* __restrict__ freq, const float2* __restrict__ H) {
  const int f = threadIdx.x;
  const int c = blockIdx.x;
  const int b = blockIdx.y;
  const float decay = 1.0f / (1.0f + expf(-log_decay[f]));
  const float om = freq[f] * 0.1f;
  const float rc = cosf(om), rs = sinf(om);
  const float Ar = decay * rc;
  const float Ai = decay * rs;
  const int t0 = c * CHUNK_L;
  float* base = sp + (size_t)b * PS * PF2;
  float2 h0 = H[((size_t)b * NCHUNK + c) * PNF + f];
  float hr = h0.x, hi = h0.y;
  for (int t = t0; t < t0 + CHUNK_L; ++t) {
    float* p = base + (size_t)t * PF2;
    float ur = p[f];
    float ui = p[PNF + f];
    float pr = fmaf(Ar, hr, fmaf(-Ai, hi, ur));
    float pi = fmaf(Ar, hi, fmaf(Ai, hr, ui));
    hr = pr; hi = pi;
    p[f]       = fmaf(rc, hr, -rs * hi);   // y.real
    p[PNF + f] = fmaf(rc, hi,  rs * hr);   // y.imag
  }
}

extern "C" void kernel_launch(void* const* d_in, const int* in_sizes, int n_in,
                              void* d_out, int out_size, void* d_ws, size_t ws_size,
                              hipStream_t stream) {
  const float* x         = (const float*)d_in[0];  // [B,S,D]
  const float* W_in      = (const float*)d_in[1];  // [2NF, D]
  const float* W_out     = (const float*)d_in[2];  // [D, 2NF]
  const float* log_decay = (const float*)d_in[3];  // [NF]
  const float* freq      = (const float*)d_in[4];  // [NF]
  float* out = (float*)d_out;                      // [B,S,D]

  float* spectral = (float*)d_ws;                          // 32768*512 f32 = 64MB
  float2* Hbuf = (float2*)(spectral + (size_t)PM * PF2);   // B*NCHUNK*NF float2 = 512KB

  // GEMM1: spectral = x @ W_in^T   (M=32768, N=512, K=1024)
  gemm_nt_f32<<<dim3(PF2 / BN, PM / BM), 256, 0, stream>>>(
      x, W_in, spectral, PM, PF2, PD);

  // Scan (in-place spectral -> feats)
  scan_warm<<<dim3(NCHUNK, PB), 256, 0, stream>>>(spectral, log_decay, freq, Hbuf);
  scan_main<<<dim3(NCHUNK, PB), 256, 0, stream>>>(spectral, log_decay, freq, Hbuf);

  // GEMM2: out = feats @ W_out^T   (M=32768, N=1024, K=512)
  gemm_nt_f32<<<dim3(PD / BN, PM / BM), 256, 0, stream>>>(
      spectral, W_out, out, PM, PD, PF2);
}

// Round 2
// 363.977 us; speedup vs baseline: 2.6975x; 2.6975x over previous
//
#include <hip/hip_runtime.h>
#include <math.h>
#include <stdint.h>

// Problem constants
#define PB 4
#define PS 8192
#define PD 1024
#define PNF 256
#define PF2 512
#define PM 32768

// Scan chunking: |A| <= sigmoid(-0.001)=0.49994 -> |A|^32 ~ 2.3e-10, warm-up
// of 32 steps reproduces the chunk-entry state exactly to fp32.
#define CHUNK_L 32
#define WARM_W 32
#define NCHUNK (PS / CHUNK_L)   // 256

typedef __bf16 bf16x8 __attribute__((ext_vector_type(8)));
typedef float f32x4 __attribute__((ext_vector_type(4)));

__device__ __forceinline__ unsigned short f2bf(float f) {
  uint32_t b = __float_as_uint(f);
  b += 0x7FFFu + ((b >> 16) & 1u);   // round-to-nearest-even
  return (unsigned short)(b >> 16);
}
__device__ __forceinline__ float bf2f(unsigned short u) {
  return __uint_as_float(((uint32_t)u) << 16);
}

__device__ __forceinline__ void gload16(const void* g, void* l) {
  __builtin_amdgcn_global_load_lds(
      (const __attribute__((address_space(1))) void*)g,
      (__attribute__((address_space(3))) void*)l, 16, 0, 0);
}

// ---------------- fp32 -> bf16 conversion, 8 elems/thread ----------------
__global__ __launch_bounds__(256) void cvt_f32_bf16(
    const float* __restrict__ in, unsigned short* __restrict__ out, int n8) {
  int i = blockIdx.x * 256 + threadIdx.x;
  const int stride = gridDim.x * 256;
  for (; i < n8; i += stride) {
    const float4* p = (const float4*)(in + (size_t)i * 8);
    float4 a = p[0], b = p[1];
    float v[8] = {a.x, a.y, a.z, a.w, b.x, b.y, b.z, b.w};
    union { unsigned short u[8]; uint4 q; } o;
#pragma unroll
    for (int j = 0; j < 8; ++j) o.u[j] = f2bf(v[j]);
    *(uint4*)(out + (size_t)i * 8) = o.q;
  }
}

// ---------------- bf16 MFMA GEMM, NT layout (m97 structure) ----------------
// C[M,N] = A[M,K] * Bt[N,K]^T ; A,Bt bf16 K-contiguous; C fp32 or bf16.
// 128x128 tile, BK=32, 4 waves (2x2), each wave 64x64 via 4x4 16x16x32 frags.
template <bool STORE_BF16>
__global__ __launch_bounds__(256, 2) void gemm_nt_mfma(
    const unsigned short* __restrict__ A, const unsigned short* __restrict__ Bt,
    void* __restrict__ Cv, int M, int N, int K) {
  __shared__ __align__(16) unsigned short As[128 * 32];
  __shared__ __align__(16) unsigned short Bs[128 * 32];
  const int tid = threadIdx.x;
  const int lane = tid & 63;
  const int w = tid >> 6;
  const int bm = blockIdx.y * 128;
  const int bn = blockIdx.x * 128;
  const int wm = (w >> 1) * 64;
  const int wn = (w & 1) * 64;

  // staging: issue i stages 64 rows (4 lanes x 16B per row); LDS dest is
  // wave-uniform base + lane*16 (HW rule), so LDS layout is linear [128][32].
  const int lr = tid >> 2;          // row 0..63 within half-tile
  const int lc = (tid & 3) * 8;     // k-col element offset
  const unsigned short* Ap = A + (size_t)(bm + lr) * K + lc;
  const unsigned short* Bp = Bt + (size_t)(bn + lr) * K + lc;
  char* AsB0 = (char*)As + (size_t)(w * 64) * 16;
  char* AsB1 = (char*)As + (size_t)(256 + w * 64) * 16;
  char* BsB0 = (char*)Bs + (size_t)(w * 64) * 16;
  char* BsB1 = (char*)Bs + (size_t)(256 + w * 64) * 16;

  const int fr = lane & 15;         // M (or N) index within fragment
  const int fk = (lane >> 4) * 8;   // K element offset within fragment

  f32x4 acc[4][4] = {};

  const int nk = K >> 5;
  for (int kk = 0; kk < nk; ++kk) {
    __syncthreads();                 // previous iter's LDS reads done
    gload16(Ap, AsB0);
    gload16(Ap + (size_t)64 * K, AsB1);
    gload16(Bp, BsB0);
    gload16(Bp + (size_t)64 * K, BsB1);
    Ap += 32; Bp += 32;
    __syncthreads();                 // compiler drains vmcnt(0) before barrier

    bf16x8 af[4], bfr[4];
#pragma unroll
    for (int mi = 0; mi < 4; ++mi)
      af[mi] = *(const bf16x8*)&As[(wm + mi * 16 + fr) * 32 + fk];
#pragma unroll
    for (int ni = 0; ni < 4; ++ni)
      bfr[ni] = *(const bf16x8*)&Bs[(wn + ni * 16 + fr) * 32 + fk];
#pragma unroll
    for (int mi = 0; mi < 4; ++mi)
#pragma unroll
      for (int ni = 0; ni < 4; ++ni)
        acc[mi][ni] = __builtin_amdgcn_mfma_f32_16x16x32_bf16(
            af[mi], bfr[ni], acc[mi][ni], 0, 0, 0);
  }

  // C/D layout (m89-verified): col = lane&15, row = (lane>>4)*4 + reg
  const int orow0 = bm + wm + (lane >> 4) * 4;
  const int ocol0 = bn + wn + (lane & 15);
  if (STORE_BF16) {
    unsigned short* C = (unsigned short*)Cv;
#pragma unroll
    for (int mi = 0; mi < 4; ++mi)
#pragma unroll
      for (int ni = 0; ni < 4; ++ni) {
        const int col = ocol0 + ni * 16;
#pragma unroll
        for (int j = 0; j < 4; ++j) {
          const int row = orow0 + mi * 16 + j;
          C[(size_t)row * N + col] = f2bf(acc[mi][ni][j]);
        }
      }
  } else {
    float* C = (float*)Cv;
#pragma unroll
    for (int mi = 0; mi < 4; ++mi)
#pragma unroll
      for (int ni = 0; ni < 4; ++ni) {
        const int col = ocol0 + ni * 16;
#pragma unroll
        for (int j = 0; j < 4; ++j) {
          const int row = orow0 + mi * 16 + j;
          C[(size_t)row * N + col] = acc[mi][ni][j];
        }
      }
  }
}

// ---------------- fused warm+main scan ----------------
// Each thread owns 2 adjacent complex features (packed-bf16 4B loads/stores).
// Block = 256 threads = 2 chunks x 128 feature-pairs. feats != spectral, so
// warm reads are race-free and no separate warm kernel is needed.
__global__ __launch_bounds__(256) void scan_fused(
    const unsigned short* __restrict__ sp, const float* __restrict__ log_decay,
    const float* __restrict__ freq, unsigned short* __restrict__ feats) {
  const int tid = threadIdx.x;
  const int half = tid >> 7;        // which chunk of the pair
  const int fp = tid & 127;         // feature-pair id
  const int f0 = fp * 2;
  const int c = blockIdx.x * 2 + half;
  const int b = blockIdx.y;

  float Ar[2], Ai[2], rc_[2], rs_[2], hr[2] = {0.f, 0.f}, hi[2] = {0.f, 0.f};
#pragma unroll
  for (int k = 0; k < 2; ++k) {
    const float decay = 1.f / (1.f + expf(-log_decay[f0 + k]));
    const float om = freq[f0 + k] * 0.1f;
    rc_[k] = cosf(om); rs_[k] = sinf(om);
    Ar[k] = decay * rc_[k]; Ai[k] = decay * rs_[k];
  }

  const int t0 = c * CHUNK_L;
  int tw = t0 - WARM_W; if (tw < 0) tw = 0;
  const uint32_t* base = (const uint32_t*)(sp + (size_t)b * PS * PF2);
  uint32_t* ob = (uint32_t*)(feats + (size_t)b * PS * PF2);
  const int pr_off = f0 >> 1;                 // uint index of real pair
  const int pi_off = (PNF + f0) >> 1;         // uint index of imag pair

  for (int t = tw; t < t0; ++t) {
    const size_t rowu = (size_t)t * (PF2 / 2);
    uint32_t pr = base[rowu + pr_off];
    uint32_t pi = base[rowu + pi_off];
    float ur[2] = {bf2f((unsigned short)(pr & 0xffff)), bf2f((unsigned short)(pr >> 16))};
    float ui[2] = {bf2f((unsigned short)(pi & 0xffff)), bf2f((unsigned short)(pi >> 16))};
#pragma unroll
    for (int k = 0; k < 2; ++k) {
      float nr = fmaf(Ar[k], hr[k], fmaf(-Ai[k], hi[k], ur[k]));
      float ni = fmaf(Ar[k], hi[k], fmaf(Ai[k], hr[k], ui[k]));
      hr[k] = nr; hi[k] = ni;
    }
  }
  for (int t = t0; t < t0 + CHUNK_L; ++t) {
    const size_t rowu = (size_t)t * (PF2 / 2);
    uint32_t pr = base[rowu + pr_off];
    uint32_t pi = base[rowu + pi_off];
    float ur[2] = {bf2f((unsigned short)(pr & 0xffff)), bf2f((unsigned short)(pr >> 16))};
    float ui[2] = {bf2f((unsigned short)(pi & 0xffff)), bf2f((unsigned short)(pi >> 16))};
    uint32_t wr = 0, wi = 0;
#pragma unroll
    for (int k = 0; k < 2; ++k) {
      float nr = fmaf(Ar[k], hr[k], fmaf(-Ai[k], hi[k], ur[k]));
      float ni = fmaf(Ar[k], hi[k], fmaf(Ai[k], hr[k], ui[k]));
      hr[k] = nr; hi[k] = ni;
      const float yr = fmaf(rc_[k], hr[k], -rs_[k] * hi[k]);
      const float yi = fmaf(rc_[k], hi[k],  rs_[k] * hr[k]);
      wr |= (uint32_t)f2bf(yr) << (16 * k);
      wi |= (uint32_t)f2bf(yi) << (16 * k);
    }
    ob[rowu + pr_off] = wr;
    ob[rowu + pi_off] = wi;
  }
}

extern "C" void kernel_launch(void* const* d_in, const int* in_sizes, int n_in,
                              void* d_out, int out_size, void* d_ws, size_t ws_size,
                              hipStream_t stream) {
  const float* x         = (const float*)d_in[0];  // [B,S,D]
  const float* W_in      = (const float*)d_in[1];  // [2NF, D]
  const float* W_out     = (const float*)d_in[2];  // [D, 2NF]
  const float* log_decay = (const float*)d_in[3];  // [NF]
  const float* freq      = (const float*)d_in[4];  // [NF]
  float* out = (float*)d_out;                      // [B,S,D] fp32

  unsigned short* xbf   = (unsigned short*)d_ws;          // PM*PD bf16 (67MB)
  unsigned short* wibf  = xbf + (size_t)PM * PD;          // 512x1024
  unsigned short* wobf  = wibf + (size_t)PF2 * PD;        // 1024x512
  unsigned short* spbf  = wobf + (size_t)PD * PF2;        // PM*PF2 bf16 (33.5MB)
  unsigned short* feats = xbf;  // reuse: GEMM1 finished with xbf before scan

  cvt_f32_bf16<<<2048, 256, 0, stream>>>(x, xbf, PM * PD / 8);
  cvt_f32_bf16<<<256, 256, 0, stream>>>(W_in, wibf, PF2 * PD / 8);
  cvt_f32_bf16<<<256, 256, 0, stream>>>(W_out, wobf, PD * PF2 / 8);

  // GEMM1: spectral(bf16) = x @ W_in^T   (M=32768, N=512, K=1024)
  gemm_nt_mfma<true><<<dim3(PF2 / 128, PM / 128), 256, 0, stream>>>(
      xbf, wibf, spbf, PM, PF2, PD);

  // fused scan: spectral(bf16) -> feats(bf16), in fp32 recurrence
  scan_fused<<<dim3(NCHUNK / 2, PB), 256, 0, stream>>>(spbf, log_decay, freq, feats);

  // GEMM2: out(fp32) = feats @ W_out^T   (M=32768, N=1024, K=512)
  gemm_nt_mfma<false><<<dim3(PD / 128, PM / 128), 256, 0, stream>>>(
      feats, wobf, out, PM, PD, PF2);
}

// Round 3
// 351.151 us; speedup vs baseline: 2.7960x; 1.0365x over previous
//
#include <hip/hip_runtime.h>
#include <math.h>
#include <stdint.h>

// Problem constants
#define PB 4
#define PS 8192
#define PD 1024
#define PNF 256
#define PF2 512
#define PM 32768

// Scan chunking: |A| <= sigmoid(-0.001)=0.49994 -> |A|^32 ~ 2.3e-10
#define CHUNK_L 32
#define WARM_W 32
#define NCHUNK (PS / CHUNK_L)   // 256

typedef __bf16 bf16x8 __attribute__((ext_vector_type(8)));
typedef float f32x4 __attribute__((ext_vector_type(4)));

__device__ __forceinline__ unsigned short f2bf(float f) {
  uint32_t b = __float_as_uint(f);
  b += 0x7FFFu + ((b >> 16) & 1u);   // RNE
  return (unsigned short)(b >> 16);
}
__device__ __forceinline__ float bf2f(unsigned short u) {
  return __uint_as_float(((uint32_t)u) << 16);
}
__device__ __forceinline__ void gload16(const void* g, void* l) {
  __builtin_amdgcn_global_load_lds(
      (const __attribute__((address_space(1))) void*)g,
      (__attribute__((address_space(3))) void*)l, 16, 0, 0);
}

// ---------------- fp32 -> bf16 conversion ----------------
__global__ __launch_bounds__(256) void cvt_f32_bf16(
    const float* __restrict__ in, unsigned short* __restrict__ out, int n8) {
  int i = blockIdx.x * 256 + threadIdx.x;
  const int stride = gridDim.x * 256;
  for (; i < n8; i += stride) {
    const float4* p = (const float4*)(in + (size_t)i * 8);
    float4 a = p[0], b = p[1];
    float v[8] = {a.x, a.y, a.z, a.w, b.x, b.y, b.z, b.w};
    union { unsigned short u[8]; uint4 q; } o;
#pragma unroll
    for (int j = 0; j < 8; ++j) o.u[j] = f2bf(v[j]);
    *(uint4*)(out + (size_t)i * 8) = o.q;
  }
}

// ---------------- 256x256 8-phase bf16 MFMA GEMM (NT) ----------------
// C[M,N] = A[M,K]*Bt[N,K]^T. 512 thr = 8 waves (2M x 4N), BK=64, LDS 128KB
// double-buffer, st_16x32 swizzle, counted vmcnt(6), raw s_barrier, setprio.
// Interleaved frag mapping: qm selects A half (rows 0-127 / 128-255), qn
// selects B half, so each LDS half-region is ds_read in exactly one phase.
template <bool STORE_BF16>
__global__ __launch_bounds__(512, 2) void gemm_nt_8phase(
    const unsigned short* __restrict__ Ag, const unsigned short* __restrict__ Bg,
    void* __restrict__ Cv, int M, int N, int K) {
  extern __shared__ char smem[];
  char* AtC = smem;              // [2][32KB] A tiles
  char* BtC = smem + 65536;      // [2][32KB] B tiles
  const int tid = threadIdx.x;
  const int lane = tid & 63;
  const int w = tid >> 6;
  const int wr = w >> 2, wc = w & 3;
  const int bm = blockIdx.y * 256, bn = blockIdx.x * 256;
  const int fr = lane & 15;
  const int fkb = (lane >> 4) * 16;          // k-group byte offset
  const int sx = ((fr >> 2) & 1) << 5;       // read-side swizzle (bit9 == row bit2)
  const int ko0 = fkb ^ sx;                  // ks=0 swizzled col byte
  const int ko1 = (64 + fkb) ^ sx;           // ks=1
  // staging: LDS dest linear tid*16; global source pre-swizzled (involution)
  const int srow = tid >> 3;                                   // 0..63
  const int scol = ((tid & 7) * 8) ^ (((tid >> 5) & 1) << 4);  // elems
  const unsigned short* Ab = Ag + (size_t)(bm + srow) * K + scol;
  const unsigned short* Bb = Bg + (size_t)(bn + srow) * K + scol;
  const int ldst = tid * 16;

  f32x4 acc[2][2][4][2] = {};
  bf16x8 af[4][2], bq[2][2];

#define STG_A(kt, h, bs) { \
    const unsigned short* g_ = Ab + (size_t)((h) * 128) * K + (kt) * 64; \
    char* l_ = AtC + ((bs) << 15) + ((h) << 14) + ldst; \
    gload16(g_, l_); gload16(g_ + (size_t)64 * K, l_ + 8192); }
#define STG_B(kt, h, bs) { \
    const unsigned short* g_ = Bb + (size_t)((h) * 128) * K + (kt) * 64; \
    char* l_ = BtC + ((bs) << 15) + ((h) << 14) + ldst; \
    gload16(g_, l_); gload16(g_ + (size_t)64 * K, l_ + 8192); }
#define LDA(bs, QM) { _Pragma("unroll") for (int mi = 0; mi < 4; ++mi) { \
    const char* p_ = AtC + ((bs) << 15) + (((QM) * 128 + wr * 64 + mi * 16 + fr) << 7); \
    af[mi][0] = *(const bf16x8*)(p_ + ko0); af[mi][1] = *(const bf16x8*)(p_ + ko1); } }
#define LDB(bs, QN) { _Pragma("unroll") for (int ni = 0; ni < 2; ++ni) { \
    const char* p_ = BtC + ((bs) << 15) + (((QN) * 128 + wc * 32 + ni * 16 + fr) << 7); \
    bq[ni][0] = *(const bf16x8*)(p_ + ko0); bq[ni][1] = *(const bf16x8*)(p_ + ko1); } }
#define MM(QM, QN) { _Pragma("unroll") for (int mi = 0; mi < 4; ++mi) \
    _Pragma("unroll") for (int ni = 0; ni < 2; ++ni) { \
      acc[QM][QN][mi][ni] = __builtin_amdgcn_mfma_f32_16x16x32_bf16( \
          af[mi][0], bq[ni][0], acc[QM][QN][mi][ni], 0, 0, 0); \
      acc[QM][QN][mi][ni] = __builtin_amdgcn_mfma_f32_16x16x32_bf16( \
          af[mi][1], bq[ni][1], acc[QM][QN][mi][ni], 0, 0, 0); } }
#define BAR() __builtin_amdgcn_s_barrier()
#define WL0() { asm volatile("s_waitcnt lgkmcnt(0)" ::: "memory"); \
                __builtin_amdgcn_sched_barrier(0); }
#define VM6() asm volatile("s_waitcnt vmcnt(6)" ::: "memory")
#define P1() __builtin_amdgcn_s_setprio(1)
#define P0() __builtin_amdgcn_s_setprio(0)

  // Prologue: tile0 {A0,B1,A1,B0} + tile1 {A0,B1,A1}; vmcnt(6) => tile0 landed
  STG_A(0, 0, 0); STG_B(0, 1, 0); STG_A(0, 1, 0); STG_B(0, 0, 0);
  STG_A(1, 0, 1); STG_B(1, 1, 1); STG_A(1, 1, 1);
  VM6();
  BAR();

  const int iters = K >> 7;   // 2 K-tiles (BK=64) per iteration
  for (int i = 0; i < iters; ++i) {
    const int o1 = 2 * i + 1, e2 = 2 * i + 2, o3 = 2 * i + 3;
    // p1 (tile 2i, buf0, qm0 qn0) -- stage B0(tile 2i+1)->buf1
    LDA(0, 0); LDB(0, 0); STG_B(o1, 0, 1);
    BAR(); WL0(); P1(); MM(0, 0); P0(); BAR();
    // p2 (qm0 qn1) -- stage A0(2i+2)->buf0 (A-half0 last read at p1)
    LDB(0, 1); STG_A(e2, 0, 0);
    BAR(); WL0(); P1(); MM(0, 1); P0(); BAR();
    // p3 (qm1 qn1) -- stage B1(2i+2) (B-half1 last read at p2)
    LDA(0, 1); STG_B(e2, 1, 0);
    BAR(); WL0(); P1(); MM(1, 1); P0(); BAR();
    // p4 (qm1 qn0, re-read B0) -- stage A1(2i+2); fence: tile 2i+1 landed
    LDB(0, 0); STG_A(e2, 1, 0);
    VM6();
    BAR(); WL0(); P1(); MM(1, 0); P0(); BAR();
    // p5 (tile 2i+1, buf1, qm0 qn0) -- stage B0(2i+2) (buf0 B0 last read p4)
    LDA(1, 0); LDB(1, 0); STG_B(e2, 0, 0);
    BAR(); WL0(); P1(); MM(0, 0); P0(); BAR();
    // p6 (qm0 qn1) -- stage A0(2i+3)->buf1
    LDB(1, 1); STG_A(o3, 0, 1);
    BAR(); WL0(); P1(); MM(0, 1); P0(); BAR();
    // p7 (qm1 qn1) -- stage B1(2i+3)
    LDA(1, 1); STG_B(o3, 1, 1);
    BAR(); WL0(); P1(); MM(1, 1); P0(); BAR();
    // p8 (qm1 qn0) -- stage A1(2i+3); fence: tile 2i+2 landed
    LDB(1, 0); STG_A(o3, 1, 1);
    VM6();
    BAR(); WL0(); P1(); MM(1, 0); P0(); BAR();
  }

  // Epilogue: C/D layout col=lane&15, row=(lane>>4)*4+j (m89-verified)
  const int crow = bm + wr * 64 + (lane >> 4) * 4;
  const int ccol = bn + wc * 32 + fr;
#pragma unroll
  for (int qm = 0; qm < 2; ++qm)
#pragma unroll
    for (int qn = 0; qn < 2; ++qn)
#pragma unroll
      for (int mi = 0; mi < 4; ++mi)
#pragma unroll
        for (int ni = 0; ni < 2; ++ni) {
          const int col = ccol + qn * 128 + ni * 16;
          if (STORE_BF16) {
            unsigned short* C = (unsigned short*)Cv;
#pragma unroll
            for (int j = 0; j < 4; ++j)
              C[(size_t)(crow + qm * 128 + mi * 16 + j) * N + col] =
                  f2bf(acc[qm][qn][mi][ni][j]);
          } else {
            float* C = (float*)Cv;
#pragma unroll
            for (int j = 0; j < 4; ++j)
              C[(size_t)(crow + qm * 128 + mi * 16 + j) * N + col] =
                  acc[qm][qn][mi][ni][j];
          }
        }
#undef STG_A
#undef STG_B
#undef LDA
#undef LDB
#undef MM
}

// ---------------- fused warm+main scan (unchanged, passed R2) ----------------
__global__ __launch_bounds__(256) void scan_fused(
    const unsigned short* __restrict__ sp, const float* __restrict__ log_decay,
    const float* __restrict__ freq, unsigned short* __restrict__ feats) {
  const int tid = threadIdx.x;
  const int half = tid >> 7;
  const int fp = tid & 127;
  const int f0 = fp * 2;
  const int c = blockIdx.x * 2 + half;
  const int b = blockIdx.y;

  float Ar[2], Ai[2], rc_[2], rs_[2], hr[2] = {0.f, 0.f}, hi[2] = {0.f, 0.f};
#pragma unroll
  for (int k = 0; k < 2; ++k) {
    const float decay = 1.f / (1.f + expf(-log_decay[f0 + k]));
    const float om = freq[f0 + k] * 0.1f;
    rc_[k] = cosf(om); rs_[k] = sinf(om);
    Ar[k] = decay * rc_[k]; Ai[k] = decay * rs_[k];
  }

  const int t0 = c * CHUNK_L;
  int tw = t0 - WARM_W; if (tw < 0) tw = 0;
  const uint32_t* base = (const uint32_t*)(sp + (size_t)b * PS * PF2);
  uint32_t* ob = (uint32_t*)(feats + (size_t)b * PS * PF2);
  const int pr_off = f0 >> 1;
  const int pi_off = (PNF + f0) >> 1;

  for (int t = tw; t < t0; ++t) {
    const size_t rowu = (size_t)t * (PF2 / 2);
    uint32_t pr = base[rowu + pr_off];
    uint32_t pi = base[rowu + pi_off];
    float ur[2] = {bf2f((unsigned short)(pr & 0xffff)), bf2f((unsigned short)(pr >> 16))};
    float ui[2] = {bf2f((unsigned short)(pi & 0xffff)), bf2f((unsigned short)(pi >> 16))};
#pragma unroll
    for (int k = 0; k < 2; ++k) {
      float nr = fmaf(Ar[k], hr[k], fmaf(-Ai[k], hi[k], ur[k]));
      float ni = fmaf(Ar[k], hi[k], fmaf(Ai[k], hr[k], ui[k]));
      hr[k] = nr; hi[k] = ni;
    }
  }
  for (int t = t0; t < t0 + CHUNK_L; ++t) {
    const size_t rowu = (size_t)t * (PF2 / 2);
    uint32_t pr = base[rowu + pr_off];
    uint32_t pi = base[rowu + pi_off];
    float ur[2] = {bf2f((unsigned short)(pr & 0xffff)), bf2f((unsigned short)(pr >> 16))};
    float ui[2] = {bf2f((unsigned short)(pi & 0xffff)), bf2f((unsigned short)(pi >> 16))};
    uint32_t wr_ = 0, wi_ = 0;
#pragma unroll
    for (int k = 0; k < 2; ++k) {
      float nr = fmaf(Ar[k], hr[k], fmaf(-Ai[k], hi[k], ur[k]));
      float ni = fmaf(Ar[k], hi[k], fmaf(Ai[k], hr[k], ui[k]));
      hr[k] = nr; hi[k] = ni;
      const float yr = fmaf(rc_[k], hr[k], -rs_[k] * hi[k]);
      const float yi = fmaf(rc_[k], hi[k],  rs_[k] * hr[k]);
      wr_ |= (uint32_t)f2bf(yr) << (16 * k);
      wi_ |= (uint32_t)f2bf(yi) << (16 * k);
    }
    ob[rowu + pr_off] = wr_;
    ob[rowu + pi_off] = wi_;
  }
}

extern "C" void kernel_launch(void* const* d_in, const int* in_sizes, int n_in,
                              void* d_out, int out_size, void* d_ws, size_t ws_size,
                              hipStream_t stream) {
  const float* x         = (const float*)d_in[0];  // [B,S,D]
  const float* W_in      = (const float*)d_in[1];  // [2NF, D]
  const float* W_out     = (const float*)d_in[2];  // [D, 2NF]
  const float* log_decay = (const float*)d_in[3];  // [NF]
  const float* freq      = (const float*)d_in[4];  // [NF]
  float* out = (float*)d_out;                      // [B,S,D] fp32

  // ws layout (elems), each matrix padded +16K elems for harmless OOB staging
  unsigned short* xbf  = (unsigned short*)d_ws;                 // 33,554,432
  unsigned short* wibf = xbf + (size_t)PM * PD + 16384;         // 524,288
  unsigned short* wobf = wibf + (size_t)PF2 * PD + 16384;       // 524,288
  unsigned short* spbf = wobf + (size_t)PD * PF2 + 16384;       // 16,777,216
  unsigned short* feats = xbf;  // reuse: GEMM1 done with xbf before scan

  cvt_f32_bf16<<<2048, 256, 0, stream>>>(x, xbf, PM * PD / 8);
  cvt_f32_bf16<<<256, 256, 0, stream>>>(W_in, wibf, PF2 * PD / 8);
  cvt_f32_bf16<<<256, 256, 0, stream>>>(W_out, wobf, PD * PF2 / 8);

  // GEMM1: spectral(bf16) = x @ W_in^T   (M=32768, N=512, K=1024)
  gemm_nt_8phase<true><<<dim3(PF2 / 256, PM / 256), 512, 131072, stream>>>(
      xbf, wibf, spbf, PM, PF2, PD);

  // fused scan: spectral(bf16) -> feats(bf16), fp32 recurrence
  scan_fused<<<dim3(NCHUNK / 2, PB), 256, 0, stream>>>(spbf, log_decay, freq, feats);

  // GEMM2: out(fp32) = feats @ W_out^T   (M=32768, N=1024, K=512)
  gemm_nt_8phase<false><<<dim3(PD / 256, PM / 256), 512, 131072, stream>>>(
      feats, wobf, out, PM, PD, PF2);
}

// Round 7
// 346.356 us; speedup vs baseline: 2.8347x; 1.0138x over previous
//
#include <hip/hip_runtime.h>
#include <math.h>
#include <stdint.h>

// Problem constants
#define PB 4
#define PS 8192
#define PD 1024
#define PNF 256
#define PF2 512
#define PM 32768

// Scan chunking: |A| <= sigmoid(-0.001)=0.49994 -> |A|^32 ~ 2.3e-10
#define CHUNK_L 32
#define WARM_W 32
#define NCHUNK (PS / CHUNK_L)   // 256

typedef __bf16 bf16x8 __attribute__((ext_vector_type(8)));
typedef float f32x4 __attribute__((ext_vector_type(4)));

__device__ __forceinline__ unsigned short f2bf(float f) {
  uint32_t b = __float_as_uint(f);
  b += 0x7FFFu + ((b >> 16) & 1u);   // RNE
  return (unsigned short)(b >> 16);
}
__device__ __forceinline__ float bf2f(unsigned short u) {
  return __uint_as_float(((uint32_t)u) << 16);
}
__device__ __forceinline__ void gload16(const void* g, void* l) {
  __builtin_amdgcn_global_load_lds(
      (const __attribute__((address_space(1))) void*)g,
      (__attribute__((address_space(3))) void*)l, 16, 0, 0);
}

// T1: bijective XCD swizzle (grid %8==0): consecutive logical ids -> same XCD
__device__ __forceinline__ int xcd_swz(int nwg) {
  const int b0 = blockIdx.y * gridDim.x + blockIdx.x;
  const int cpx = nwg >> 3;
  return (b0 & 7) * cpx + (b0 >> 3);
}

// ---------------- fp32 -> bf16 conversion ----------------
__global__ __launch_bounds__(256) void cvt_f32_bf16(
    const float* __restrict__ in, unsigned short* __restrict__ out, int n8) {
  int i = blockIdx.x * 256 + threadIdx.x;
  const int stride = gridDim.x * 256;
  for (; i < n8; i += stride) {
    const float4* p = (const float4*)(in + (size_t)i * 8);
    float4 a = p[0], b = p[1];
    float v[8] = {a.x, a.y, a.z, a.w, b.x, b.y, b.z, b.w};
    union { unsigned short u[8]; uint4 q; } o;
#pragma unroll
    for (int j = 0; j < 8; ++j) o.u[j] = f2bf(v[j]);
    *(uint4*)(out + (size_t)i * 8) = o.q;
  }
}

// ---------------- 256x256 8-phase bf16 MFMA GEMM (NT) — r3-proven + T1 -----
// C[M,N] = A[M,K]*Bt[N,K]^T. 512 thr = 8 waves (2M x 4N), BK=64, LDS 128KB
// double-buffer, st_16x32 swizzle, counted vmcnt(6), raw s_barrier, setprio.
template <bool STORE_BF16>
__global__ __launch_bounds__(512, 2) void gemm_nt_8phase(
    const unsigned short* __restrict__ Ag, const unsigned short* __restrict__ Bg,
    void* __restrict__ Cv, int M, int N, int K) {
  extern __shared__ char smem[];
  char* AtC = smem;              // [2][32KB] A tiles
  char* BtC = smem + 65536;      // [2][32KB] B tiles
  const int tid = threadIdx.x;
  const int lane = tid & 63;
  const int w = tid >> 6;
  const int wr = w >> 2, wc = w & 3;
  const int l = xcd_swz(gridDim.x * gridDim.y);           // T1 (only change vs r3)
  const int bn = (l % gridDim.x) * 256, bm = (l / gridDim.x) * 256;
  const int fr = lane & 15;
  const int fkb = (lane >> 4) * 16;          // k-group byte offset
  const int sx = ((fr >> 2) & 1) << 5;       // read-side swizzle (bit9 == row bit2)
  const int ko0 = fkb ^ sx;                  // ks=0 swizzled col byte
  const int ko1 = (64 + fkb) ^ sx;           // ks=1
  // staging: LDS dest linear tid*16; global source pre-swizzled (involution)
  const int srow = tid >> 3;                                   // 0..63
  const int scol = ((tid & 7) * 8) ^ (((tid >> 5) & 1) << 4);  // elems
  const unsigned short* Ab = Ag + (size_t)(bm + srow) * K + scol;
  const unsigned short* Bb = Bg + (size_t)(bn + srow) * K + scol;
  const int ldst = tid * 16;

  f32x4 acc[2][2][4][2] = {};
  bf16x8 af[4][2], bq[2][2];

#define STG_A(kt, h, bs) { \
    const unsigned short* g_ = Ab + (size_t)((h) * 128) * K + (kt) * 64; \
    char* l_ = AtC + ((bs) << 15) + ((h) << 14) + ldst; \
    gload16(g_, l_); gload16(g_ + (size_t)64 * K, l_ + 8192); }
#define STG_B(kt, h, bs) { \
    const unsigned short* g_ = Bb + (size_t)((h) * 128) * K + (kt) * 64; \
    char* l_ = BtC + ((bs) << 15) + ((h) << 14) + ldst; \
    gload16(g_, l_); gload16(g_ + (size_t)64 * K, l_ + 8192); }
#define LDA(bs, QM) { _Pragma("unroll") for (int mi = 0; mi < 4; ++mi) { \
    const char* p_ = AtC + ((bs) << 15) + (((QM) * 128 + wr * 64 + mi * 16 + fr) << 7); \
    af[mi][0] = *(const bf16x8*)(p_ + ko0); af[mi][1] = *(const bf16x8*)(p_ + ko1); } }
#define LDB(bs, QN) { _Pragma("unroll") for (int ni = 0; ni < 2; ++ni) { \
    const char* p_ = BtC + ((bs) << 15) + (((QN) * 128 + wc * 32 + ni * 16 + fr) << 7); \
    bq[ni][0] = *(const bf16x8*)(p_ + ko0); bq[ni][1] = *(const bf16x8*)(p_ + ko1); } }
#define MM(QM, QN) { _Pragma("unroll") for (int mi = 0; mi < 4; ++mi) \
    _Pragma("unroll") for (int ni = 0; ni < 2; ++ni) { \
      acc[QM][QN][mi][ni] = __builtin_amdgcn_mfma_f32_16x16x32_bf16( \
          af[mi][0], bq[ni][0], acc[QM][QN][mi][ni], 0, 0, 0); \
      acc[QM][QN][mi][ni] = __builtin_amdgcn_mfma_f32_16x16x32_bf16( \
          af[mi][1], bq[ni][1], acc[QM][QN][mi][ni], 0, 0, 0); } }
#define BAR() __builtin_amdgcn_s_barrier()
#define WL0() { asm volatile("s_waitcnt lgkmcnt(0)" ::: "memory"); \
                __builtin_amdgcn_sched_barrier(0); }
#define VM6() asm volatile("s_waitcnt vmcnt(6)" ::: "memory")
#define P1() __builtin_amdgcn_s_setprio(1)
#define P0() __builtin_amdgcn_s_setprio(0)

  // Prologue: tile0 {A0,B1,A1,B0} + tile1 {A0,B1,A1}; vmcnt(6) => tile0 landed
  STG_A(0, 0, 0); STG_B(0, 1, 0); STG_A(0, 1, 0); STG_B(0, 0, 0);
  STG_A(1, 0, 1); STG_B(1, 1, 1); STG_A(1, 1, 1);
  VM6();
  BAR();

  const int iters = K >> 7;   // 2 K-tiles (BK=64) per iteration
  for (int i = 0; i < iters; ++i) {
    const int o1 = 2 * i + 1, e2 = 2 * i + 2, o3 = 2 * i + 3;
    // p1 (tile 2i, buf0, qm0 qn0) -- stage B0(tile 2i+1)->buf1
    LDA(0, 0); LDB(0, 0); STG_B(o1, 0, 1);
    BAR(); WL0(); P1(); MM(0, 0); P0(); BAR();
    // p2 (qm0 qn1) -- stage A0(2i+2)->buf0 (A-half0 last read at p1)
    LDB(0, 1); STG_A(e2, 0, 0);
    BAR(); WL0(); P1(); MM(0, 1); P0(); BAR();
    // p3 (qm1 qn1) -- stage B1(2i+2) (B-half1 last read at p2)
    LDA(0, 1); STG_B(e2, 1, 0);
    BAR(); WL0(); P1(); MM(1, 1); P0(); BAR();
    // p4 (qm1 qn0, re-read B0) -- stage A1(2i+2); fence: tile 2i+1 landed
    LDB(0, 0); STG_A(e2, 1, 0);
    VM6();
    BAR(); WL0(); P1(); MM(1, 0); P0(); BAR();
    // p5 (tile 2i+1, buf1, qm0 qn0) -- stage B0(2i+2) (buf0 B0 last read p4)
    LDA(1, 0); LDB(1, 0); STG_B(e2, 0, 0);
    BAR(); WL0(); P1(); MM(0, 0); P0(); BAR();
    // p6 (qm0 qn1) -- stage A0(2i+3)->buf1
    LDB(1, 1); STG_A(o3, 0, 1);
    BAR(); WL0(); P1(); MM(0, 1); P0(); BAR();
    // p7 (qm1 qn1) -- stage B1(2i+3)
    LDA(1, 1); STG_B(o3, 1, 1);
    BAR(); WL0(); P1(); MM(1, 1); P0(); BAR();
    // p8 (qm1 qn0) -- stage A1(2i+3); fence: tile 2i+2 landed
    LDB(1, 0); STG_A(o3, 1, 1);
    VM6();
    BAR(); WL0(); P1(); MM(1, 0); P0(); BAR();
  }

  // Epilogue: C/D layout col=lane&15, row=(lane>>4)*4+j (m89-verified)
  const int crow = bm + wr * 64 + (lane >> 4) * 4;
  const int ccol = bn + wc * 32 + fr;
#pragma unroll
  for (int qm = 0; qm < 2; ++qm)
#pragma unroll
    for (int qn = 0; qn < 2; ++qn)
#pragma unroll
      for (int mi = 0; mi < 4; ++mi)
#pragma unroll
        for (int ni = 0; ni < 2; ++ni) {
          const int col = ccol + qn * 128 + ni * 16;
          if (STORE_BF16) {
            unsigned short* C = (unsigned short*)Cv;
#pragma unroll
            for (int j = 0; j < 4; ++j)
              C[(size_t)(crow + qm * 128 + mi * 16 + j) * N + col] =
                  f2bf(acc[qm][qn][mi][ni][j]);
          } else {
            float* C = (float*)Cv;
#pragma unroll
            for (int j = 0; j < 4; ++j)
              C[(size_t)(crow + qm * 128 + mi * 16 + j) * N + col] =
                  acc[qm][qn][mi][ni][j];
          }
        }
#undef STG_A
#undef STG_B
#undef LDA
#undef LDB
#undef MM
}

// ---------------- fused warm+main scan (unchanged, passes) ----------------
__global__ __launch_bounds__(256) void scan_fused(
    const unsigned short* __restrict__ sp, const float* __restrict__ log_decay,
    const float* __restrict__ freq, unsigned short* __restrict__ feats) {
  const int tid = threadIdx.x;
  const int half = tid >> 7;
  const int fp = tid & 127;
  const int f0 = fp * 2;
  const int c = blockIdx.x * 2 + half;
  const int b = blockIdx.y;

  float Ar[2], Ai[2], rc_[2], rs_[2], hr[2] = {0.f, 0.f}, hi[2] = {0.f, 0.f};
#pragma unroll
  for (int k = 0; k < 2; ++k) {
    const float decay = 1.f / (1.f + expf(-log_decay[f0 + k]));
    const float om = freq[f0 + k] * 0.1f;
    rc_[k] = cosf(om); rs_[k] = sinf(om);
    Ar[k] = decay * rc_[k]; Ai[k] = decay * rs_[k];
  }

  const int t0 = c * CHUNK_L;
  int tw = t0 - WARM_W; if (tw < 0) tw = 0;
  const uint32_t* base = (const uint32_t*)(sp + (size_t)b * PS * PF2);
  uint32_t* ob = (uint32_t*)(feats + (size_t)b * PS * PF2);
  const int pr_off = f0 >> 1;
  const int pi_off = (PNF + f0) >> 1;

  for (int t = tw; t < t0; ++t) {
    const size_t rowu = (size_t)t * (PF2 / 2);
    uint32_t pr = base[rowu + pr_off];
    uint32_t pi = base[rowu + pi_off];
    float ur[2] = {bf2f((unsigned short)(pr & 0xffff)), bf2f((unsigned short)(pr >> 16))};
    float ui[2] = {bf2f((unsigned short)(pi & 0xffff)), bf2f((unsigned short)(pi >> 16))};
#pragma unroll
    for (int k = 0; k < 2; ++k) {
      float nr = fmaf(Ar[k], hr[k], fmaf(-Ai[k], hi[k], ur[k]));
      float ni = fmaf(Ar[k], hi[k], fmaf(Ai[k], hr[k], ui[k]));
      hr[k] = nr; hi[k] = ni;
    }
  }
  for (int t = t0; t < t0 + CHUNK_L; ++t) {
    const size_t rowu = (size_t)t * (PF2 / 2);
    uint32_t pr = base[rowu + pr_off];
    uint32_t pi = base[rowu + pi_off];
    float ur[2] = {bf2f((unsigned short)(pr & 0xffff)), bf2f((unsigned short)(pr >> 16))};
    float ui[2] = {bf2f((unsigned short)(pi & 0xffff)), bf2f((unsigned short)(pi >> 16))};
    uint32_t wr_ = 0, wi_ = 0;
#pragma unroll
    for (int k = 0; k < 2; ++k) {
      float nr = fmaf(Ar[k], hr[k], fmaf(-Ai[k], hi[k], ur[k]));
      float ni = fmaf(Ar[k], hi[k], fmaf(Ai[k], hr[k], ui[k]));
      hr[k] = nr; hi[k] = ni;
      const float yr = fmaf(rc_[k], hr[k], -rs_[k] * hi[k]);
      const float yi = fmaf(rc_[k], hi[k],  rs_[k] * hr[k]);
      wr_ |= (uint32_t)f2bf(yr) << (16 * k);
      wi_ |= (uint32_t)f2bf(yi) << (16 * k);
    }
    ob[rowu + pr_off] = wr_;
    ob[rowu + pi_off] = wi_;
  }
}

extern "C" void kernel_launch(void* const* d_in, const int* in_sizes, int n_in,
                              void* d_out, int out_size, void* d_ws, size_t ws_size,
                              hipStream_t stream) {
  const float* x         = (const float*)d_in[0];  // [B,S,D]
  const float* W_in      = (const float*)d_in[1];  // [2NF, D]
  const float* W_out     = (const float*)d_in[2];  // [D, 2NF]
  const float* log_decay = (const float*)d_in[3];  // [NF]
  const float* freq      = (const float*)d_in[4];  // [NF]
  float* out = (float*)d_out;                      // [B,S,D] fp32

  // ws layout (elems), each matrix padded +16K elems for harmless OOB staging
  unsigned short* xbf  = (unsigned short*)d_ws;                 // 33,554,432
  unsigned short* wibf = xbf + (size_t)PM * PD + 16384;         // 524,288
  unsigned short* wobf = wibf + (size_t)PF2 * PD + 16384;       // 524,288
  unsigned short* spbf = wobf + (size_t)PD * PF2 + 16384;       // 16,777,216
  unsigned short* feats = xbf;  // reuse: GEMM1 done with xbf before scan

  cvt_f32_bf16<<<2048, 256, 0, stream>>>(x, xbf, PM * PD / 8);
  cvt_f32_bf16<<<256, 256, 0, stream>>>(W_in, wibf, PF2 * PD / 8);
  cvt_f32_bf16<<<256, 256, 0, stream>>>(W_out, wobf, PD * PF2 / 8);

  // GEMM1: spectral(bf16) = x @ W_in^T   (M=32768, N=512, K=1024)
  gemm_nt_8phase<true><<<dim3(PF2 / 256, PM / 256), 512, 131072, stream>>>(
      xbf, wibf, spbf, PM, PF2, PD);

  // fused scan: spectral(bf16) -> feats(bf16), fp32 recurrence
  scan_fused<<<dim3(NCHUNK / 2, PB), 256, 0, stream>>>(spbf, log_decay, freq, feats);

  // GEMM2: out(fp32) = feats @ W_out^T   (M=32768, N=1024, K=512)
  gemm_nt_8phase<false><<<dim3(PD / 256, PM / 256), 512, 131072, stream>>>(
      feats, wobf, out, PM, PD, PF2);
}